// Round 3
// baseline (3233.833 us; speedup 1.0000x reference)
//
#include <hip/hip_runtime.h>
#include <hip/hip_bf16.h>

#define N_NODES  100000
#define N_EDGES  1600000
#define N_GRAPHS 2048
#define EMBED    64
#define HID      64
#define N_CL     2

// ---------------- degree ----------------
__global__ __launch_bounds__(256) void k_deg(const int* __restrict__ col, int* __restrict__ deg) {
    int e = blockIdx.x * 256 + threadIdx.x;
    if (e < N_EDGES) atomicAdd(&deg[col[e]], 1);
}

__global__ __launch_bounds__(256) void k_dinv(const int* __restrict__ deg, float* __restrict__ dinv) {
    int v = blockIdx.x * 256 + threadIdx.x;
    if (v < N_NODES) dinv[v] = rsqrtf((float)(deg[v] + 1));   // +1 = self loop
}

// ---------------- layer 1: tn[v] = dinv[v] * (emb[x[v]] @ W1) ----------------
__global__ __launch_bounds__(256) void k_gemm_embed(const int* __restrict__ x,
                                                    const float* __restrict__ emb,
                                                    const float* __restrict__ W,
                                                    const float* __restrict__ dinv,
                                                    float* __restrict__ tn) {
    int gtid = blockIdx.x * 256 + threadIdx.x;
    int v = gtid >> 6;
    int f = gtid & 63;
    if (v >= N_NODES) return;
    const float* hr = emb + x[v] * EMBED;
    float acc = 0.f;
#pragma unroll
    for (int k = 0; k < EMBED; ++k)
        acc += hr[k] * W[k * HID + f];
    tn[gtid] = acc * dinv[v];
}

// ---------------- layer 2: tn[v] = dinv[v] * (h[v] @ W2) ----------------
__global__ __launch_bounds__(256) void k_gemm(const float* __restrict__ h,
                                              const float* __restrict__ W,
                                              const float* __restrict__ dinv,
                                              float* __restrict__ tn) {
    int gtid = blockIdx.x * 256 + threadIdx.x;
    int v = gtid >> 6;
    int f = gtid & 63;
    if (v >= N_NODES) return;
    const float* hr = h + v * HID;
    float acc = 0.f;
#pragma unroll
    for (int k = 0; k < HID; ++k)
        acc += hr[k] * W[k * HID + f];
    tn[gtid] = acc * dinv[v];
}

// ---------------- edge scatter: agg[col] += tn[row]  (16 threads/edge, float4 each) ----------------
__global__ __launch_bounds__(256) void k_scatter(const int* __restrict__ row,
                                                 const int* __restrict__ col,
                                                 const float* __restrict__ tn,
                                                 float* __restrict__ agg) {
    int t = blockIdx.x * 256 + threadIdx.x;
    int e = t >> 4;
    int p = t & 15;
    if (e >= N_EDGES) return;
    int r = row[e];
    int c = col[e];
    float4 v = ((const float4*)(tn + r * HID))[p];
    float* dst = agg + c * HID + p * 4;
    atomicAdd(dst + 0, v.x);
    atomicAdd(dst + 1, v.y);
    atomicAdd(dst + 2, v.z);
    atomicAdd(dst + 3, v.w);
}

// ---------------- finalize in place: agg = relu(dinv*(agg + tn) + b) ----------------
__global__ __launch_bounds__(256) void k_finalize(float* __restrict__ agg,
                                                  const float* __restrict__ tn,
                                                  const float* __restrict__ dinv,
                                                  const float* __restrict__ b) {
    int gtid = blockIdx.x * 256 + threadIdx.x;
    int v = gtid >> 6;
    int f = gtid & 63;
    if (v >= N_NODES) return;
    float val = dinv[v] * (agg[gtid] + tn[gtid]) + b[f];
    agg[gtid] = fmaxf(val, 0.f);
}

// ---------------- mean-pool accumulation ----------------
__global__ __launch_bounds__(256) void k_pool(const float* __restrict__ h,
                                              const int* __restrict__ batch,
                                              float* __restrict__ sums,
                                              int* __restrict__ cnt) {
    int t = blockIdx.x * 256 + threadIdx.x;
    int v = t >> 4;
    int p = t & 15;
    if (v >= N_NODES) return;
    int g = batch[v];
    float4 val = ((const float4*)(h + v * HID))[p];
    float* dst = sums + g * HID + p * 4;
    atomicAdd(dst + 0, val.x);
    atomicAdd(dst + 1, val.y);
    atomicAdd(dst + 2, val.z);
    atomicAdd(dst + 3, val.w);
    if (p == 0) atomicAdd(&cnt[g], 1);
}

// ---------------- final projection: out[g][c] = mean(h) @ Wl + bl  (fp32 out) ----------------
__global__ __launch_bounds__(256) void k_out(const float* __restrict__ sums,
                                             const int* __restrict__ cnt,
                                             const float* __restrict__ Wl,
                                             const float* __restrict__ bl,
                                             float* __restrict__ out) {
    int t = blockIdx.x * 256 + threadIdx.x;
    if (t >= N_GRAPHS * N_CL) return;
    int g = t / N_CL;
    int c = t % N_CL;
    float inv = 1.f / fmaxf((float)cnt[g], 1.f);
    float acc = 0.f;
#pragma unroll
    for (int f = 0; f < HID; ++f)
        acc += sums[g * HID + f] * Wl[f * N_CL + c];
    out[t] = acc * inv + bl[c];
}

extern "C" void kernel_launch(void* const* d_in, const int* in_sizes, int n_in,
                              void* d_out, int out_size, void* d_ws, size_t ws_size,
                              hipStream_t stream) {
    const int*   x     = (const int*)d_in[0];
    const int*   ei    = (const int*)d_in[1];        // [2, E] flat: sources then targets
    const int*   batch = (const int*)d_in[2];
    const float* emb   = (const float*)d_in[3];
    const float* W1    = (const float*)d_in[4];
    const float* b1    = (const float*)d_in[5];
    const float* W2    = (const float*)d_in[6];
    const float* b2    = (const float*)d_in[7];
    const float* Wl    = (const float*)d_in[8];
    const float* bl    = (const float*)d_in[9];
    float* out = (float*)d_out;

    const int* row = ei;             // sources
    const int* col = ei + N_EDGES;   // targets

    // workspace layout: two big feature buffers + small arrays (~52.5 MB total)
    char* ws = (char*)d_ws;
    const size_t FEAT_BYTES = (size_t)N_NODES * HID * sizeof(float);   // 25,600,000
    float* A    = (float*)(ws);                      // tn (pre-scatter messages)
    float* B    = (float*)(ws + FEAT_BYTES);         // agg -> h (in-place finalize)
    char*  tail = ws + 2 * FEAT_BYTES;
    float* sums = (float*)(tail);                                      // 2048*64 f32
    float* dinv = (float*)(tail + (size_t)N_GRAPHS * HID * sizeof(float));
    int*   deg  = (int*)  (tail + (size_t)N_GRAPHS * HID * sizeof(float)
                                + (size_t)N_NODES * sizeof(float));
    int*   cnt  = (int*)  ((char*)deg + (size_t)N_NODES * sizeof(int));

    const int NF = N_NODES * HID;             // 6.4M
    dim3 blk(256);
    dim3 g_deg((N_EDGES + 255) / 256);
    dim3 g_n((N_NODES + 255) / 256);
    dim3 g_nf(NF / 256);                      // 25000
    dim3 g_sc((N_EDGES * 16) / 256);          // 100000
    dim3 g_pool((N_NODES * 16 + 255) / 256);  // 6250
    dim3 g_out((N_GRAPHS * N_CL + 255) / 256);

    // zero: deg + cnt (contiguous), sums
    hipMemsetAsync(deg, 0, (size_t)N_NODES * sizeof(int) + (size_t)N_GRAPHS * sizeof(int), stream);
    hipMemsetAsync(sums, 0, (size_t)N_GRAPHS * HID * sizeof(float), stream);

    k_deg<<<g_deg, blk, 0, stream>>>(col, deg);
    k_dinv<<<g_n, blk, 0, stream>>>(deg, dinv);

    // ---- layer 1 ----
    k_gemm_embed<<<g_nf, blk, 0, stream>>>(x, emb, W1, dinv, A);
    hipMemsetAsync(B, 0, FEAT_BYTES, stream);
    k_scatter<<<g_sc, blk, 0, stream>>>(row, col, A, B);
    k_finalize<<<g_nf, blk, 0, stream>>>(B, A, dinv, b1);   // B = h1

    // ---- layer 2 ----
    k_gemm<<<g_nf, blk, 0, stream>>>(B, W2, dinv, A);       // A = tn2 (B fully consumed)
    hipMemsetAsync(B, 0, FEAT_BYTES, stream);
    k_scatter<<<g_sc, blk, 0, stream>>>(row, col, A, B);
    k_finalize<<<g_nf, blk, 0, stream>>>(B, A, dinv, b2);   // B = h2

    // ---- pool + classify ----
    k_pool<<<g_pool, blk, 0, stream>>>(B, batch, sums, cnt);
    k_out<<<g_out, blk, 0, stream>>>(sums, cnt, Wl, bl, out);
}

// Round 5
// 734.490 us; speedup vs baseline: 4.4028x; 4.4028x over previous
//
#include <hip/hip_runtime.h>
#include <hip/hip_bf16.h>

#define N_NODES  100000
#define N_EDGES  1600000
#define N_GRAPHS 2048
#define EMBED    64
#define HID      64
#define N_CL     2
#define NBLK     391   // ceil(N_NODES/256)

// ---------------- degree (in-degree over real edges) ----------------
__global__ __launch_bounds__(256) void k_deg(const int* __restrict__ col, int* __restrict__ deg) {
    int e = blockIdx.x * 256 + threadIdx.x;
    if (e < N_EDGES) atomicAdd(&deg[col[e]], 1);
}

__global__ __launch_bounds__(256) void k_dinv(const int* __restrict__ deg, float* __restrict__ dinv) {
    int v = blockIdx.x * 256 + threadIdx.x;
    if (v < N_NODES) dinv[v] = rsqrtf((float)(deg[v] + 1));   // +1 = self loop
}

// ---------------- CSR build: block sums -> single-block scan -> per-block scan ----------------
__global__ __launch_bounds__(256) void k_bsum(const int* __restrict__ deg, int* __restrict__ bsum) {
    __shared__ int s[256];
    int i = blockIdx.x * 256 + threadIdx.x;
    s[threadIdx.x] = (i < N_NODES) ? deg[i] : 0;
    __syncthreads();
    for (int off = 128; off > 0; off >>= 1) {
        if (threadIdx.x < off) s[threadIdx.x] += s[threadIdx.x + off];
        __syncthreads();
    }
    if (threadIdx.x == 0) bsum[blockIdx.x] = s[0];
}

// exclusive scan of bsum (NBLK entries) in place; single block, barrier-ordered so in-place is safe
__global__ __launch_bounds__(512) void k_scan_small(int* __restrict__ bsum) {
    __shared__ int s[512];
    int t = threadIdx.x;
    s[t] = (t < NBLK) ? bsum[t] : 0;
    __syncthreads();
    for (int off = 1; off < 512; off <<= 1) {
        int v = (t >= off) ? s[t - off] : 0;
        __syncthreads();
        s[t] += v;
        __syncthreads();
    }
    if (t < NBLK) bsum[t] = (t == 0) ? 0 : s[t - 1];
}

__global__ __launch_bounds__(256) void k_scan_final(const int* __restrict__ deg, const int* __restrict__ boff,
                                                    int* __restrict__ rowptr) {
    __shared__ int s[256];
    int t = threadIdx.x;
    int i = blockIdx.x * 256 + t;
    s[t] = (i < N_NODES) ? deg[i] : 0;
    __syncthreads();
    for (int off = 1; off < 256; off <<= 1) {
        int v = (t >= off) ? s[t - off] : 0;
        __syncthreads();
        s[t] += v;
        __syncthreads();
    }
    if (i < N_NODES) rowptr[i + 1] = boff[blockIdx.x] + s[t];
    if (blockIdx.x == 0 && t == 0) rowptr[0] = 0;
}

__global__ __launch_bounds__(256) void k_fill(const int* __restrict__ row, const int* __restrict__ col,
                                              const int* __restrict__ rowptr, int* __restrict__ cursor,
                                              int* __restrict__ nbr) {
    int e = blockIdx.x * 256 + threadIdx.x;
    if (e >= N_EDGES) return;
    int c = col[e];
    int pos = rowptr[c] + atomicAdd(&cursor[c], 1);
    nbr[pos] = row[e];
}

// ---------------- layer 1: tn[v] = dinv[v] * (emb[x[v]] @ W1) ----------------
__global__ __launch_bounds__(256) void k_gemm_embed(const int* __restrict__ x,
                                                    const float* __restrict__ emb,
                                                    const float* __restrict__ W,
                                                    const float* __restrict__ dinv,
                                                    float* __restrict__ tn) {
    int gtid = blockIdx.x * 256 + threadIdx.x;
    int v = gtid >> 6;
    int f = gtid & 63;
    if (v >= N_NODES) return;
    const float* hr = emb + x[v] * EMBED;
    float acc = 0.f;
#pragma unroll
    for (int k = 0; k < EMBED; ++k)
        acc += hr[k] * W[k * HID + f];
    tn[gtid] = acc * dinv[v];
}

// ---------------- layer 2: tn[v] = dinv[v] * (h[v] @ W2) ----------------
__global__ __launch_bounds__(256) void k_gemm(const float* __restrict__ h,
                                              const float* __restrict__ W,
                                              const float* __restrict__ dinv,
                                              float* __restrict__ tn) {
    int gtid = blockIdx.x * 256 + threadIdx.x;
    int v = gtid >> 6;
    int f = gtid & 63;
    if (v >= N_NODES) return;
    const float* hr = h + v * HID;
    float acc = 0.f;
#pragma unroll
    for (int k = 0; k < HID; ++k)
        acc += hr[k] * W[k * HID + f];
    tn[gtid] = acc * dinv[v];
}

// ---------------- fused gather-aggregate + self-loop + bias + relu ----------------
// one wave per node; lane = feature
__global__ __launch_bounds__(256) void k_agg(const float* __restrict__ tn,
                                             const int* __restrict__ rowptr,
                                             const int* __restrict__ nbr,
                                             const float* __restrict__ dinv,
                                             const float* __restrict__ bias,
                                             float* __restrict__ h) {
    int v = (blockIdx.x * 256 + threadIdx.x) >> 6;
    int f = threadIdx.x & 63;
    if (v >= N_NODES) return;
    int s = rowptr[v], e = rowptr[v + 1];
    float acc = tn[v * HID + f];          // self loop
    int i = s;
    for (; i + 4 <= e; i += 4) {
        int n0 = nbr[i], n1 = nbr[i + 1], n2 = nbr[i + 2], n3 = nbr[i + 3];
        float a0 = tn[n0 * HID + f];
        float a1 = tn[n1 * HID + f];
        float a2 = tn[n2 * HID + f];
        float a3 = tn[n3 * HID + f];
        acc += (a0 + a1) + (a2 + a3);
    }
    for (; i < e; ++i) acc += tn[nbr[i] * HID + f];
    h[v * HID + f] = fmaxf(dinv[v] * acc + bias[f], 0.f);
}

// ---------------- mean-pool accumulation ----------------
__global__ __launch_bounds__(256) void k_pool(const float* __restrict__ h,
                                              const int* __restrict__ batch,
                                              float* __restrict__ sums,
                                              int* __restrict__ cnt) {
    int t = blockIdx.x * 256 + threadIdx.x;
    int v = t >> 4;
    int p = t & 15;
    if (v >= N_NODES) return;
    int g = batch[v];
    float4 val = ((const float4*)(h + v * HID))[p];
    float* dst = sums + g * HID + p * 4;
    atomicAdd(dst + 0, val.x);
    atomicAdd(dst + 1, val.y);
    atomicAdd(dst + 2, val.z);
    atomicAdd(dst + 3, val.w);
    if (p == 0) atomicAdd(&cnt[g], 1);
}

// ---------------- final projection (fp32 out) ----------------
__global__ __launch_bounds__(256) void k_out(const float* __restrict__ sums,
                                             const int* __restrict__ cnt,
                                             const float* __restrict__ Wl,
                                             const float* __restrict__ bl,
                                             float* __restrict__ out) {
    int t = blockIdx.x * 256 + threadIdx.x;
    if (t >= N_GRAPHS * N_CL) return;
    int g = t / N_CL;
    int c = t % N_CL;
    float inv = 1.f / fmaxf((float)cnt[g], 1.f);
    float acc = 0.f;
#pragma unroll
    for (int f = 0; f < HID; ++f)
        acc += sums[g * HID + f] * Wl[f * N_CL + c];
    out[t] = acc * inv + bl[c];
}

extern "C" void kernel_launch(void* const* d_in, const int* in_sizes, int n_in,
                              void* d_out, int out_size, void* d_ws, size_t ws_size,
                              hipStream_t stream) {
    const int*   x     = (const int*)d_in[0];
    const int*   ei    = (const int*)d_in[1];        // [2, E] flat: sources then targets
    const int*   batch = (const int*)d_in[2];
    const float* emb   = (const float*)d_in[3];
    const float* W1    = (const float*)d_in[4];
    const float* b1    = (const float*)d_in[5];
    const float* W2    = (const float*)d_in[6];
    const float* b2    = (const float*)d_in[7];
    const float* Wl    = (const float*)d_in[8];
    const float* bl    = (const float*)d_in[9];
    float* out = (float*)d_out;

    const int* row = ei;             // sources
    const int* col = ei + N_EDGES;   // targets

    // ---- workspace layout (~60 MB) ----
    char* ws = (char*)d_ws;
    size_t off = 0;
    auto alloc = [&](size_t bytes) { char* p = ws + off; off = (off + bytes + 511) & ~(size_t)511; return p; };
    const size_t FEAT_BYTES = (size_t)N_NODES * HID * sizeof(float);   // 25.6 MB
    float* A      = (float*)alloc(FEAT_BYTES);                 // tn
    float* B      = (float*)alloc(FEAT_BYTES);                 // h
    int*   nbr    = (int*)  alloc((size_t)N_EDGES * sizeof(int));       // 6.4 MB
    int*   rowptr = (int*)  alloc((size_t)(N_NODES + 1) * sizeof(int));
    float* dinv   = (float*)alloc((size_t)N_NODES * sizeof(float));
    int*   bsum   = (int*)  alloc((size_t)NBLK * sizeof(int));
    // contiguous zeroed region: deg | cursor | cnt | sums
    char*  zbase  = ws + off;
    int*   deg    = (int*)  alloc((size_t)N_NODES * sizeof(int));
    int*   cursor = (int*)  alloc((size_t)N_NODES * sizeof(int));
    int*   cnt    = (int*)  alloc((size_t)N_GRAPHS * sizeof(int));
    float* sums   = (float*)alloc((size_t)N_GRAPHS * HID * sizeof(float));
    size_t zbytes = (size_t)((ws + off) - zbase);

    dim3 blk(256);
    dim3 g_e((N_EDGES + 255) / 256);
    dim3 g_n((N_NODES + 255) / 256);          // = NBLK
    dim3 g_nf(N_NODES * HID / 256);           // 25000
    dim3 g_agg((N_NODES * 64 + 255) / 256);   // 25000
    dim3 g_pool((N_NODES * 16 + 255) / 256);
    dim3 g_out((N_GRAPHS * N_CL + 255) / 256);

    hipMemsetAsync(zbase, 0, zbytes, stream);

    // ---- graph structure (shared by both layers) ----
    k_deg<<<g_e, blk, 0, stream>>>(col, deg);
    k_dinv<<<g_n, blk, 0, stream>>>(deg, dinv);
    k_bsum<<<NBLK, blk, 0, stream>>>(deg, bsum);
    k_scan_small<<<1, 512, 0, stream>>>(bsum);            // ONCE: bsum -> exclusive block offsets
    k_scan_final<<<NBLK, blk, 0, stream>>>(deg, bsum, rowptr);
    k_fill<<<g_e, blk, 0, stream>>>(row, col, rowptr, cursor, nbr);

    // ---- layer 1 ----
    k_gemm_embed<<<g_nf, blk, 0, stream>>>(x, emb, W1, dinv, A);
    k_agg<<<g_agg, blk, 0, stream>>>(A, rowptr, nbr, dinv, b1, B);

    // ---- layer 2 ----
    k_gemm<<<g_nf, blk, 0, stream>>>(B, W2, dinv, A);
    k_agg<<<g_agg, blk, 0, stream>>>(A, rowptr, nbr, dinv, b2, B);

    // ---- pool + classify ----
    k_pool<<<g_pool, blk, 0, stream>>>(B, batch, sums, cnt);
    k_out<<<g_out, blk, 0, stream>>>(sums, cnt, Wl, bl, out);
}

// Round 6
// 513.918 us; speedup vs baseline: 6.2925x; 1.4292x over previous
//
#include <hip/hip_runtime.h>
#include <hip/hip_bf16.h>

#define N_NODES  100000
#define N_EDGES  1600000
#define N_GRAPHS 2048
#define EMBED    64
#define HID      64
#define N_CL     2
#define NBLK     391   // ceil(N_NODES/256)

// ---------------- degree (in-degree over real edges) ----------------
__global__ __launch_bounds__(256) void k_deg(const int* __restrict__ col, int* __restrict__ deg) {
    int e = blockIdx.x * 256 + threadIdx.x;
    if (e < N_EDGES) atomicAdd(&deg[col[e]], 1);
}

__global__ __launch_bounds__(256) void k_dinv(const int* __restrict__ deg, float* __restrict__ dinv) {
    int v = blockIdx.x * 256 + threadIdx.x;
    if (v < N_NODES) dinv[v] = rsqrtf((float)(deg[v] + 1));   // +1 = self loop
}

// ---------------- CSR build: block sums -> single-block scan -> per-block scan ----------------
__global__ __launch_bounds__(256) void k_bsum(const int* __restrict__ deg, int* __restrict__ bsum) {
    __shared__ int s[256];
    int i = blockIdx.x * 256 + threadIdx.x;
    s[threadIdx.x] = (i < N_NODES) ? deg[i] : 0;
    __syncthreads();
    for (int off = 128; off > 0; off >>= 1) {
        if (threadIdx.x < off) s[threadIdx.x] += s[threadIdx.x + off];
        __syncthreads();
    }
    if (threadIdx.x == 0) bsum[blockIdx.x] = s[0];
}

// exclusive scan of bsum (NBLK entries) in place; single block, barrier-ordered
__global__ __launch_bounds__(512) void k_scan_small(int* __restrict__ bsum) {
    __shared__ int s[512];
    int t = threadIdx.x;
    s[t] = (t < NBLK) ? bsum[t] : 0;
    __syncthreads();
    for (int off = 1; off < 512; off <<= 1) {
        int v = (t >= off) ? s[t - off] : 0;
        __syncthreads();
        s[t] += v;
        __syncthreads();
    }
    if (t < NBLK) bsum[t] = (t == 0) ? 0 : s[t - 1];
}

__global__ __launch_bounds__(256) void k_scan_final(const int* __restrict__ deg, const int* __restrict__ boff,
                                                    int* __restrict__ rowptr) {
    __shared__ int s[256];
    int t = threadIdx.x;
    int i = blockIdx.x * 256 + t;
    s[t] = (i < N_NODES) ? deg[i] : 0;
    __syncthreads();
    for (int off = 1; off < 256; off <<= 1) {
        int v = (t >= off) ? s[t - off] : 0;
        __syncthreads();
        s[t] += v;
        __syncthreads();
    }
    if (i < N_NODES) rowptr[i + 1] = boff[blockIdx.x] + s[t];
    if (blockIdx.x == 0 && t == 0) rowptr[0] = 0;
}

__global__ __launch_bounds__(256) void k_fill(const int* __restrict__ row, const int* __restrict__ col,
                                              const int* __restrict__ rowptr, int* __restrict__ cursor,
                                              int* __restrict__ nbr) {
    int e = blockIdx.x * 256 + threadIdx.x;
    if (e >= N_EDGES) return;
    int c = col[e];
    int pos = rowptr[c] + atomicAdd(&cursor[c], 1);
    nbr[pos] = row[e];
}

// ---------------- graph boundaries (batch is sorted): start[g] = first v with batch[v] >= g ----------------
__global__ __launch_bounds__(256) void k_start_init(int* __restrict__ start) {
    int g = blockIdx.x * 256 + threadIdx.x;
    if (g <= N_GRAPHS) start[g] = N_NODES;
}

__global__ __launch_bounds__(256) void k_gb(const int* __restrict__ batch, int* __restrict__ start) {
    int v = blockIdx.x * 256 + threadIdx.x;
    if (v >= N_NODES) return;
    int b = batch[v];
    int pb = (v == 0) ? -1 : batch[v - 1];
    for (int g = pb + 1; g <= b; ++g) start[g] = v;
}

// ---------------- layer 1: tn[v] = dinv[v] * (emb[x[v]] @ W1), float4 per thread ----------------
__global__ __launch_bounds__(256) void k_gemm_embed(const int* __restrict__ x,
                                                    const float* __restrict__ emb,
                                                    const float* __restrict__ W,
                                                    const float* __restrict__ dinv,
                                                    float* __restrict__ tn) {
    int t = blockIdx.x * 256 + threadIdx.x;   // N_NODES*16 threads
    int v = t >> 4;
    int f4 = t & 15;
    if (v >= N_NODES) return;
    const float4* W4 = (const float4*)W;
    const float* hr = emb + x[v] * EMBED;
    float4 acc = make_float4(0.f, 0.f, 0.f, 0.f);
#pragma unroll 8
    for (int k = 0; k < EMBED; ++k) {
        float hv = hr[k];
        float4 w = W4[k * 16 + f4];
        acc.x += hv * w.x; acc.y += hv * w.y; acc.z += hv * w.z; acc.w += hv * w.w;
    }
    float d = dinv[v];
    acc.x *= d; acc.y *= d; acc.z *= d; acc.w *= d;
    ((float4*)tn)[t] = acc;
}

// ---------------- layer 2: tn[v] = dinv[v] * (h[v] @ W2), float4 per thread ----------------
__global__ __launch_bounds__(256) void k_gemm(const float* __restrict__ h,
                                              const float* __restrict__ W,
                                              const float* __restrict__ dinv,
                                              float* __restrict__ tn) {
    int t = blockIdx.x * 256 + threadIdx.x;
    int v = t >> 4;
    int f4 = t & 15;
    if (v >= N_NODES) return;
    const float4* W4 = (const float4*)W;
    const float* hr = h + v * HID;
    float4 acc = make_float4(0.f, 0.f, 0.f, 0.f);
#pragma unroll 8
    for (int k = 0; k < HID; ++k) {
        float hv = hr[k];
        float4 w = W4[k * 16 + f4];
        acc.x += hv * w.x; acc.y += hv * w.y; acc.z += hv * w.z; acc.w += hv * w.w;
    }
    float d = dinv[v];
    acc.x *= d; acc.y *= d; acc.z *= d; acc.w *= d;
    ((float4*)tn)[t] = acc;
}

// ---------------- fused gather-aggregate + self-loop + bias + relu ----------------
// one wave per node; lane = (edge-slot es[0..3], feature-group fg[0..15]); 4 edges per iteration
__global__ __launch_bounds__(256) void k_agg(const float* __restrict__ tn,
                                             const int* __restrict__ rowptr,
                                             const int* __restrict__ nbr,
                                             const float* __restrict__ dinv,
                                             const float* __restrict__ bias,
                                             float* __restrict__ h) {
    int v = (blockIdx.x * 256 + threadIdx.x) >> 6;
    if (v >= N_NODES) return;
    int lane = threadIdx.x & 63;
    int fg = lane & 15;
    int es = lane >> 4;
    const float4* tn4 = (const float4*)tn;
    int s = rowptr[v], e = rowptr[v + 1];
    float4 acc = make_float4(0.f, 0.f, 0.f, 0.f);
    if (es == 0) acc = tn4[v * 16 + fg];          // self loop
    for (int i = s; i < e; i += 4) {
        int idx = i + es;
        if (idx < e) {
            float4 tv = tn4[nbr[idx] * 16 + fg];
            acc.x += tv.x; acc.y += tv.y; acc.z += tv.z; acc.w += tv.w;
        }
    }
    // combine the 4 edge-slots: xor across lane bits 4 (16) and 5 (32)
    acc.x += __shfl_xor(acc.x, 16, 64); acc.y += __shfl_xor(acc.y, 16, 64);
    acc.z += __shfl_xor(acc.z, 16, 64); acc.w += __shfl_xor(acc.w, 16, 64);
    acc.x += __shfl_xor(acc.x, 32, 64); acc.y += __shfl_xor(acc.y, 32, 64);
    acc.z += __shfl_xor(acc.z, 32, 64); acc.w += __shfl_xor(acc.w, 32, 64);
    if (es == 0) {
        float d = dinv[v];
        float4 bb = ((const float4*)bias)[fg];
        float4 o;
        o.x = fmaxf(d * acc.x + bb.x, 0.f);
        o.y = fmaxf(d * acc.y + bb.y, 0.f);
        o.z = fmaxf(d * acc.z + bb.z, 0.f);
        o.w = fmaxf(d * acc.w + bb.w, 0.f);
        ((float4*)h)[v * 16 + fg] = o;
    }
}

// ---------------- fused mean-pool + projection: one wave per graph, no atomics ----------------
__global__ __launch_bounds__(256) void k_pool_out(const float* __restrict__ h,
                                                  const int* __restrict__ start,
                                                  const float* __restrict__ Wl,
                                                  const float* __restrict__ bl,
                                                  float* __restrict__ out) {
    int g = (blockIdx.x * 256 + threadIdx.x) >> 6;
    int f = threadIdx.x & 63;
    if (g >= N_GRAPHS) return;
    int s = start[g], e = start[g + 1];
    float acc = 0.f;
    int v = s;
    for (; v + 4 <= e; v += 4) {
        float a0 = h[(v + 0) * HID + f];
        float a1 = h[(v + 1) * HID + f];
        float a2 = h[(v + 2) * HID + f];
        float a3 = h[(v + 3) * HID + f];
        acc += (a0 + a1) + (a2 + a3);
    }
    for (; v < e; ++v) acc += h[v * HID + f];
    float m = acc / fmaxf((float)(e - s), 1.f);
    float p0 = m * Wl[f * N_CL + 0];
    float p1 = m * Wl[f * N_CL + 1];
#pragma unroll
    for (int off = 32; off > 0; off >>= 1) {
        p0 += __shfl_down(p0, off, 64);
        p1 += __shfl_down(p1, off, 64);
    }
    if (f == 0) {
        out[g * N_CL + 0] = p0 + bl[0];
        out[g * N_CL + 1] = p1 + bl[1];
    }
}

extern "C" void kernel_launch(void* const* d_in, const int* in_sizes, int n_in,
                              void* d_out, int out_size, void* d_ws, size_t ws_size,
                              hipStream_t stream) {
    const int*   x     = (const int*)d_in[0];
    const int*   ei    = (const int*)d_in[1];        // [2, E] flat: sources then targets
    const int*   batch = (const int*)d_in[2];
    const float* emb   = (const float*)d_in[3];
    const float* W1    = (const float*)d_in[4];
    const float* b1    = (const float*)d_in[5];
    const float* W2    = (const float*)d_in[6];
    const float* b2    = (const float*)d_in[7];
    const float* Wl    = (const float*)d_in[8];
    const float* bl    = (const float*)d_in[9];
    float* out = (float*)d_out;

    const int* row = ei;             // sources
    const int* col = ei + N_EDGES;   // targets

    // ---- workspace layout (~60 MB) ----
    char* ws = (char*)d_ws;
    size_t off = 0;
    auto alloc = [&](size_t bytes) { char* p = ws + off; off = (off + bytes + 511) & ~(size_t)511; return p; };
    const size_t FEAT_BYTES = (size_t)N_NODES * HID * sizeof(float);   // 25.6 MB
    float* A      = (float*)alloc(FEAT_BYTES);                 // tn
    float* B      = (float*)alloc(FEAT_BYTES);                 // h
    int*   nbr    = (int*)  alloc((size_t)N_EDGES * sizeof(int));       // 6.4 MB
    int*   rowptr = (int*)  alloc((size_t)(N_NODES + 1) * sizeof(int));
    float* dinv   = (float*)alloc((size_t)N_NODES * sizeof(float));
    int*   bsum   = (int*)  alloc((size_t)NBLK * sizeof(int));
    int*   start  = (int*)  alloc((size_t)(N_GRAPHS + 1) * sizeof(int));
    // contiguous zeroed region: deg | cursor
    char*  zbase  = ws + off;
    int*   deg    = (int*)  alloc((size_t)N_NODES * sizeof(int));
    int*   cursor = (int*)  alloc((size_t)N_NODES * sizeof(int));
    size_t zbytes = (size_t)((ws + off) - zbase);

    dim3 blk(256);
    dim3 g_e((N_EDGES + 255) / 256);
    dim3 g_n((N_NODES + 255) / 256);              // = NBLK
    dim3 g_nf16((N_NODES * 16 + 255) / 256);      // 6250
    dim3 g_agg((N_NODES * 64 + 255) / 256);       // 25000
    dim3 g_ginit((N_GRAPHS + 1 + 255) / 256);
    dim3 g_po((N_GRAPHS * 64 + 255) / 256);       // 512

    hipMemsetAsync(zbase, 0, zbytes, stream);

    // ---- graph structure (shared by both layers) ----
    k_deg<<<g_e, blk, 0, stream>>>(col, deg);
    k_dinv<<<g_n, blk, 0, stream>>>(deg, dinv);
    k_bsum<<<NBLK, blk, 0, stream>>>(deg, bsum);
    k_scan_small<<<1, 512, 0, stream>>>(bsum);
    k_scan_final<<<NBLK, blk, 0, stream>>>(deg, bsum, rowptr);
    k_fill<<<g_e, blk, 0, stream>>>(row, col, rowptr, cursor, nbr);
    k_start_init<<<g_ginit, blk, 0, stream>>>(start);
    k_gb<<<g_n, blk, 0, stream>>>(batch, start);

    // ---- layer 1 ----
    k_gemm_embed<<<g_nf16, blk, 0, stream>>>(x, emb, W1, dinv, A);
    k_agg<<<g_agg, blk, 0, stream>>>(A, rowptr, nbr, dinv, b1, B);

    // ---- layer 2 ----
    k_gemm<<<g_nf16, blk, 0, stream>>>(B, W2, dinv, A);
    k_agg<<<g_agg, blk, 0, stream>>>(A, rowptr, nbr, dinv, b2, B);

    // ---- fused pool + classify ----
    k_pool_out<<<g_po, blk, 0, stream>>>(B, start, Wl, bl, out);
}